// Round 6
// baseline (409.042 us; speedup 1.0000x reference)
//
#include <hip/hip_runtime.h>
#include <math.h>

#define N_NODES 50000
#define E_EDGES 800000
#define D_IN    256
#define D_H     128
#define D_OUT   128

#define MT    64                          // nodes per GEMM tile
#define NBLK  ((N_NODES + MT - 1) / MT)   // 782
#define NB_DEG ((E_EDGES + 255) / 256)    // 3125

typedef __attribute__((ext_vector_type(8))) short bf16x8;
typedef __attribute__((ext_vector_type(4))) float f32x4;

__device__ __forceinline__ unsigned short f2bf(float f) {
    unsigned u = __float_as_uint(f);
    return (unsigned short)((u + 0x7FFFu + ((u >> 16) & 1u)) >> 16);
}
__device__ __forceinline__ float bf2f(unsigned short u) {
    return __uint_as_float((unsigned)u << 16);
}

// Fragment layouts (16x16x32 bf16 MFMA), verified R3-R5:
//   A-frag: lane(lm,quad) holds A[m=blk*16+lm][k=kblk*32+quad*8 ..+8]
//   B-frag: lane holds W[n=blk*16+lm][k=...]
//   C/D:    col = lane&15, row = quad*4 + reg
// Packed: chunk c = (kblk*N16 + blk)*64 + lane -> shorts c*8..+8 (lane-linear).

// ================= D1: [wconv | deg] =================
__global__ __launch_bounds__(256) void k_d1(const float* __restrict__ Wfc,
                                            const float* __restrict__ Wq,
                                            const float* __restrict__ Wk,
                                            const float* __restrict__ Wv,
                                            const float* __restrict__ Ws,
                                            unsigned short* __restrict__ wsw,
                                            const int* __restrict__ ei,
                                            int* __restrict__ deg) {
    if (blockIdx.x < 96) {
        int g = blockIdx.x * 256 + threadIdx.x;      // 0..24575 float4 groups
        const float* src; unsigned short* dst; int n, k0;
        if (g < 8192) {                               // W_fc: 128 x 256
            src = Wfc; dst = wsw;
            n = g >> 6; k0 = (g & 63) * 4;
        } else {
            int t = (g - 8192) >> 12;                 // 0..3
            int pos = (g - 8192) & 4095;              // 128 x 128
            src = (t == 0) ? Wq : (t == 1) ? Wk : (t == 2) ? Wv : Ws;
            dst = wsw + 32768 + t * 16384;
            n = pos >> 5; k0 = (pos & 31) * 4;
        }
        float4 v = *(const float4*)(src + (size_t)n * ((g < 8192) ? 256 : 128) + k0);
        unsigned r0 = (unsigned)f2bf(v.x) | ((unsigned)f2bf(v.y) << 16);
        unsigned r1 = (unsigned)f2bf(v.z) | ((unsigned)f2bf(v.w) << 16);
        int kblk = k0 >> 5, quad = (k0 & 31) >> 3, rem = k0 & 7;
        int sidx = (((kblk * 8 + (n >> 4)) * 4 + quad) * 16 + (n & 15)) * 8 + rem;
        *(uint2*)&dst[sidx] = make_uint2(r0, r1);
    } else {
        int e = (blockIdx.x - 96) * 256 + threadIdx.x;
        if (e < E_EDGES) atomicAdd(&deg[ei[E_EDGES + e]], 1);
    }
}

// ================= D2: [fc | scan] =================
__global__ __launch_bounds__(256) void k_d2(const float* __restrict__ x,
                                            const unsigned short* __restrict__ wfc,
                                            const float* __restrict__ b,
                                            unsigned short* __restrict__ hfrag,
                                            const int* __restrict__ deg,
                                            int* __restrict__ offs,
                                            int* __restrict__ cursor) {
    const int tid = threadIdx.x;
    if (blockIdx.x < NBLK) {
        // ---- fc: h = relu(x @ W_fc^T + b_fc), frag-packed bf16 out ----
        __shared__ __align__(16) unsigned short As[MT * D_IN];   // 32 KB
        const int lane = tid & 63;
        const int wid  = tid >> 6;
        const int lm   = lane & 15;
        const int quad = lane >> 4;
        const int node0 = blockIdx.x * MT;

#pragma unroll
        for (int i = 0; i < 16; ++i) {
            int idx = tid + i * 256;                 // 0..4095 float4 groups
            int row = idx >> 6;
            int k0  = (idx & 63) * 4;
            int gn  = node0 + row;
            float4 v = make_float4(0.f, 0.f, 0.f, 0.f);
            if (gn < N_NODES) v = *(const float4*)(x + (size_t)gn * D_IN + k0);
            unsigned r0 = (unsigned)f2bf(v.x) | ((unsigned)f2bf(v.y) << 16);
            unsigned r1 = (unsigned)f2bf(v.z) | ((unsigned)f2bf(v.w) << 16);
            int kblk = k0 >> 5, q4 = (k0 & 31) >> 3, rem = k0 & 7;
            int sidx = ((kblk * 4 + (row >> 4)) * 64 + q4 * 16 + (row & 15)) * 8 + rem;
            *(uint2*)&As[sidx] = make_uint2(r0, r1);
        }
        __syncthreads();

        f32x4 acc[4][2];
#pragma unroll
        for (int i = 0; i < 4; ++i)
#pragma unroll
            for (int j = 0; j < 2; ++j) { acc[i][j][0]=0.f; acc[i][j][1]=0.f; acc[i][j][2]=0.f; acc[i][j][3]=0.f; }

#pragma unroll
        for (int kb = 0; kb < 8; ++kb) {             // K = 256
            bf16x8 af[4], bfr[2];
#pragma unroll
            for (int nt = 0; nt < 4; ++nt)
                af[nt] = *(const bf16x8*)&As[(((kb * 4 + nt) * 64) + lane) * 8];
#pragma unroll
            for (int ft = 0; ft < 2; ++ft)
                bfr[ft] = *(const bf16x8*)&wfc[((kb * 8 + wid * 2 + ft) * 64 + lane) * 8];
#pragma unroll
            for (int nt = 0; nt < 4; ++nt)
#pragma unroll
                for (int ft = 0; ft < 2; ++ft)
                    acc[nt][ft] = __builtin_amdgcn_mfma_f32_16x16x32_bf16(af[nt], bfr[ft], acc[nt][ft], 0, 0, 0);
        }
        __syncthreads();                              // As dead; reuse

#pragma unroll
        for (int ft = 0; ft < 2; ++ft) {
            int feat = wid * 32 + ft * 16 + lm;
            float bb = b[feat];
#pragma unroll
            for (int nt = 0; nt < 4; ++nt)
#pragma unroll
                for (int r = 0; r < 4; ++r) {
                    float vv = fmaxf(acc[nt][ft][r] + bb, 0.f);
                    int sidx = ((wid * 4 + nt) * 64 + (ft * 2 + (lm >> 3)) * 16 + quad * 4 + r) * 8 + (lm & 7);
                    As[sidx] = f2bf(vv);
                }
        }
        __syncthreads();
        unsigned short* hdst = hfrag + (size_t)blockIdx.x * 8192;
#pragma unroll
        for (int i = 0; i < 4; ++i) {
            int idx = tid + i * 256;
            *(uint4*)(hdst + idx * 8) = *(const uint4*)&As[idx * 8];
        }
    } else {
        // ---- scan: exclusive prefix of deg -> offs, cursor (1 block) ----
        __shared__ int wsum[4];
        const int PT = 196;                          // 256*196 = 50176 >= 50000
        int base = tid * PT;
        int cnt = (base < N_NODES) ? min(PT, N_NODES - base) : 0;
        int s = 0;
        for (int i = 0; i < cnt; ++i) s += deg[base + i];
        int lane = tid & 63, w = tid >> 6;
        int v = s;
        for (int off = 1; off < 64; off <<= 1) {
            int t = __shfl_up(v, off, 64);
            if (lane >= off) v += t;
        }
        if (lane == 63) wsum[w] = v;
        __syncthreads();
        int woff = 0;
        for (int i = 0; i < w; ++i) woff += wsum[i];
        int run = woff + v - s;                      // exclusive prefix
        for (int i = 0; i < cnt; ++i) {
            offs[base + i] = run;
            cursor[base + i] = run;
            run += deg[base + i];
        }
        if (tid == 0) offs[N_NODES] = E_EDGES;
    }
}

// ================= D3: [qkvs | fill] =================
__global__ __launch_bounds__(256) void k_d3(const unsigned short* __restrict__ hfrag,
                                            const unsigned short* __restrict__ wsw,
                                            const float* __restrict__ bq,
                                            const float* __restrict__ bk,
                                            const float* __restrict__ bv,
                                            const float* __restrict__ bs,
                                            float* __restrict__ qo,
                                            unsigned short* __restrict__ kv,
                                            float* __restrict__ out,
                                            const int* __restrict__ ei,
                                            int* __restrict__ cursor,
                                            int* __restrict__ ssrc) {
    const int tid = threadIdx.x;
    if (blockIdx.x < NBLK * 4) {
        const int tile = blockIdx.x >> 2;
        const int sel  = blockIdx.x & 3;
        const unsigned short* W = wsw + 32768 + sel * 16384;
        const float* b = (sel == 0) ? bq : (sel == 1) ? bk : (sel == 2) ? bv : bs;
        const int lane = tid & 63;
        const int wid  = tid >> 6;
        const int lm   = lane & 15;
        const int quad = lane >> 4;
        const int node0 = tile * MT;
        const unsigned short* hsrc = hfrag + (size_t)tile * 8192;

        f32x4 acc[4][2];
#pragma unroll
        for (int i = 0; i < 4; ++i)
#pragma unroll
            for (int j = 0; j < 2; ++j) { acc[i][j][0]=0.f; acc[i][j][1]=0.f; acc[i][j][2]=0.f; acc[i][j][3]=0.f; }

#pragma unroll
        for (int kb = 0; kb < 4; ++kb) {             // K = 128
            bf16x8 af[4], bfr[2];
#pragma unroll
            for (int nt = 0; nt < 4; ++nt)
                af[nt] = *(const bf16x8*)&hsrc[((kb * 4 + nt) * 64 + lane) * 8];
#pragma unroll
            for (int ft = 0; ft < 2; ++ft)
                bfr[ft] = *(const bf16x8*)&W[((kb * 8 + wid * 2 + ft) * 64 + lane) * 8];
#pragma unroll
            for (int nt = 0; nt < 4; ++nt)
#pragma unroll
                for (int ft = 0; ft < 2; ++ft)
                    acc[nt][ft] = __builtin_amdgcn_mfma_f32_16x16x32_bf16(af[nt], bfr[ft], acc[nt][ft], 0, 0, 0);
        }
#pragma unroll
        for (int ft = 0; ft < 2; ++ft) {
            int feat = wid * 32 + ft * 16 + lm;
            float bb = b[feat];
#pragma unroll
            for (int nt = 0; nt < 4; ++nt)
#pragma unroll
                for (int r = 0; r < 4; ++r) {
                    int gn = node0 + nt * 16 + quad * 4 + r;
                    if (gn < N_NODES) {
                        float vv = acc[nt][ft][r] + bb;
                        if (sel == 0)      qo[(size_t)gn * D_OUT + feat] = vv;
                        else if (sel == 1) kv[(size_t)gn * 256 + feat] = f2bf(vv);
                        else if (sel == 2) kv[(size_t)gn * 256 + 128 + feat] = f2bf(vv);
                        else               out[(size_t)gn * D_OUT + feat] = vv;
                    }
                }
        }
    } else {
        int e = (blockIdx.x - NBLK * 4) * 256 + tid;
        if (e < E_EDGES) {
            int d = ei[E_EDGES + e];
            int p = atomicAdd(&cursor[d], 1);
            ssrc[p] = ei[e];
        }
    }
}

// ================= D4: aggregation =================
// one wave/node; 4 independent 16-lane groups, each owning one edge at a time.
// No running max (scores provably tiny for this model: |s| << 1), so softmax
// is a plain sum of exp — no serial rescale chain.
__global__ __launch_bounds__(256) void k_agg(const float* __restrict__ q,
                                             const unsigned short* __restrict__ kv,
                                             const int* __restrict__ offs,
                                             const int* __restrict__ ssrc,
                                             float* __restrict__ out) {
    const int wid  = threadIdx.x >> 6;
    const int lane = threadIdx.x & 63;
    const int node = blockIdx.x * 4 + wid;
    if (node >= N_NODES) return;
    const int beg = offs[node];
    const int end = offs[node + 1];
    if (beg == end) return;                       // out already holds skip

    const int g = lane >> 4;                      // group 0..3 (edge slot)
    const int c = lane & 15;                      // channel chunk (8 ch)

    float qf[8];
    {
        float4 q0 = *(const float4*)(q + (size_t)node * D_OUT + c * 8);
        float4 q1 = *(const float4*)(q + (size_t)node * D_OUT + c * 8 + 4);
        qf[0]=q0.x; qf[1]=q0.y; qf[2]=q0.z; qf[3]=q0.w;
        qf[4]=q1.x; qf[5]=q1.y; qf[6]=q1.z; qf[7]=q1.w;
    }
    const float scale = 0.08838834764831845f;     // 1/sqrt(128)
    float l = 0.f;
    float acc[8];
#pragma unroll
    for (int i = 0; i < 8; ++i) acc[i] = 0.f;

    for (int p = beg; p < end; p += 4) {
        int pg = p + g;
        int j = ssrc[(pg < end) ? pg : (end - 1)];
        bf16x8 kvec = *(const bf16x8*)(kv + (size_t)j * 256 + c * 8);
        bf16x8 vvec = *(const bf16x8*)(kv + (size_t)j * 256 + 128 + c * 8);
        float s = 0.f;
#pragma unroll
        for (int i = 0; i < 8; ++i) s += bf2f((unsigned short)kvec[i]) * qf[i];
#pragma unroll
        for (int off = 1; off < 16; off <<= 1) s += __shfl_xor(s, off, 64);
        float e = (pg < end) ? __expf(s * scale) : 0.f;
        l += e;
#pragma unroll
        for (int i = 0; i < 8; ++i) acc[i] += e * bf2f((unsigned short)vvec[i]);
    }
    // merge the 4 groups (cross-group butterfly; lanes keep same channel c)
#pragma unroll
    for (int off = 16; off < 64; off <<= 1) {
        l += __shfl_xor(l, off, 64);
#pragma unroll
        for (int i = 0; i < 8; ++i) acc[i] += __shfl_xor(acc[i], off, 64);
    }
    if (g == 0) {
        float inv = 1.f / l;
        float* orow = out + (size_t)node * D_OUT + c * 8;
        float4 o0 = *(const float4*)(orow);
        float4 o1 = *(const float4*)(orow + 4);
        o0.x += acc[0] * inv; o0.y += acc[1] * inv; o0.z += acc[2] * inv; o0.w += acc[3] * inv;
        o1.x += acc[4] * inv; o1.y += acc[5] * inv; o1.z += acc[6] * inv; o1.w += acc[7] * inv;
        *(float4*)(orow)     = o0;
        *(float4*)(orow + 4) = o1;
    }
}

// ---------------- host launch ----------------
extern "C" void kernel_launch(void* const* d_in, const int* in_sizes, int n_in,
                              void* d_out, int out_size, void* d_ws, size_t ws_size,
                              hipStream_t stream) {
    const float* x     = (const float*)d_in[0];
    const int*   ei    = (const int*)d_in[1];
    const float* W_fc  = (const float*)d_in[2];
    const float* b_fc  = (const float*)d_in[3];
    const float* W_q   = (const float*)d_in[4];
    const float* b_q   = (const float*)d_in[5];
    const float* W_k   = (const float*)d_in[6];
    const float* b_k   = (const float*)d_in[7];
    const float* W_v   = (const float*)d_in[8];
    const float* b_v   = (const float*)d_in[9];
    const float* W_s   = (const float*)d_in[10];
    const float* b_s   = (const float*)d_in[11];
    float* out = (float*)d_out;

    // ws layout: q fp32 25.6MB | kv bf16 25.6MB | hfrag bf16 12.8MB |
    //            wsw bf16 196KB | CSR ~3.8MB  => ~68 MB total (< ws_size)
    float* qb = (float*)d_ws;
    unsigned short* kvb   = (unsigned short*)(qb + (size_t)N_NODES * D_OUT);
    unsigned short* hfrag = kvb + (size_t)N_NODES * 256;
    unsigned short* wsw   = hfrag + (size_t)NBLK * 8192;
    int* deg    = (int*)(wsw + 98304);
    int* offs   = deg + N_NODES;          // N+1 entries
    int* cursor = offs + (N_NODES + 1);
    int* ssrc   = cursor + N_NODES;       // E entries

    hipMemsetAsync(deg, 0, N_NODES * sizeof(int), stream);

    k_d1<<<96 + NB_DEG, 256, 0, stream>>>(W_fc, W_q, W_k, W_v, W_s, wsw, ei, deg);
    k_d2<<<NBLK + 1, 256, 0, stream>>>(x, wsw, b_fc, hfrag, deg, offs, cursor);
    k_d3<<<NBLK * 4 + NB_DEG, 256, 0, stream>>>(hfrag, wsw, b_q, b_k, b_v, b_s,
                                                qb, kvb, out, ei, cursor, ssrc);
    k_agg<<<(N_NODES + 3) / 4, 256, 0, stream>>>(qb, kvb, offs, ssrc, out);
}

// Round 7
// 383.875 us; speedup vs baseline: 1.0656x; 1.0656x over previous
//
#include <hip/hip_runtime.h>
#include <math.h>

#define N_NODES 50000
#define E_EDGES 800000
#define D_IN    256
#define D_H     128
#define D_OUT   128

#define MT    64                          // nodes per GEMM tile
#define NBLK  ((N_NODES + MT - 1) / MT)   // 782
#define NB_DEG ((E_EDGES + 255) / 256)    // 3125

typedef __attribute__((ext_vector_type(8))) short bf16x8;
typedef __attribute__((ext_vector_type(4))) float f32x4;

__device__ __forceinline__ unsigned short f2bf(float f) {
    unsigned u = __float_as_uint(f);
    return (unsigned short)((u + 0x7FFFu + ((u >> 16) & 1u)) >> 16);
}
__device__ __forceinline__ float bf2f(unsigned short u) {
    return __uint_as_float((unsigned)u << 16);
}

// Fragment layouts (16x16x32 bf16 MFMA), verified R3-R6:
//   A-frag: lane(lm,quad) holds A[m=blk*16+lm][k=kblk*32+quad*8 ..+8]
//   B-frag: lane holds W[n=blk*16+lm][k=...]
//   C/D:    col = lane&15, row = quad*4 + reg
// Packed: chunk c = (kblk*N16 + blk)*64 + lane -> shorts c*8..+8 (lane-linear).

// ================= D1: [wconv | deg] =================
__global__ __launch_bounds__(256) void k_d1(const float* __restrict__ Wfc,
                                            const float* __restrict__ Wq,
                                            const float* __restrict__ Wk,
                                            const float* __restrict__ Wv,
                                            const float* __restrict__ Ws,
                                            unsigned short* __restrict__ wsw,
                                            const int* __restrict__ ei,
                                            int* __restrict__ deg) {
    if (blockIdx.x < 96) {
        int g = blockIdx.x * 256 + threadIdx.x;      // 0..24575 float4 groups
        const float* src; unsigned short* dst; int n, k0;
        if (g < 8192) {                               // W_fc: 128 x 256
            src = Wfc; dst = wsw;
            n = g >> 6; k0 = (g & 63) * 4;
        } else {
            int t = (g - 8192) >> 12;                 // 0..3
            int pos = (g - 8192) & 4095;              // 128 x 128
            src = (t == 0) ? Wq : (t == 1) ? Wk : (t == 2) ? Wv : Ws;
            dst = wsw + 32768 + t * 16384;
            n = pos >> 5; k0 = (pos & 31) * 4;
        }
        float4 v = *(const float4*)(src + (size_t)n * ((g < 8192) ? 256 : 128) + k0);
        unsigned r0 = (unsigned)f2bf(v.x) | ((unsigned)f2bf(v.y) << 16);
        unsigned r1 = (unsigned)f2bf(v.z) | ((unsigned)f2bf(v.w) << 16);
        int kblk = k0 >> 5, quad = (k0 & 31) >> 3, rem = k0 & 7;
        int sidx = (((kblk * 8 + (n >> 4)) * 4 + quad) * 16 + (n & 15)) * 8 + rem;
        *(uint2*)&dst[sidx] = make_uint2(r0, r1);
    } else {
        int e = (blockIdx.x - 96) * 256 + threadIdx.x;
        if (e < E_EDGES) atomicAdd(&deg[ei[E_EDGES + e]], 1);
    }
}

// ================= D2: [fc | scan] =================
__global__ __launch_bounds__(256) void k_d2(const float* __restrict__ x,
                                            const unsigned short* __restrict__ wfc,
                                            const float* __restrict__ b,
                                            unsigned short* __restrict__ hfrag,
                                            const int* __restrict__ deg,
                                            int* __restrict__ offs,
                                            int* __restrict__ cursor) {
    __shared__ __align__(16) unsigned short As[MT * D_IN];   // 32 KB, both branches
    const int tid = threadIdx.x;
    if (blockIdx.x < NBLK) {
        // ---- fc: h = relu(x @ W_fc^T + b_fc), frag-packed bf16 out ----
        const int lane = tid & 63;
        const int wid  = tid >> 6;
        const int lm   = lane & 15;
        const int quad = lane >> 4;
        const int node0 = blockIdx.x * MT;

#pragma unroll
        for (int i = 0; i < 16; ++i) {
            int idx = tid + i * 256;                 // 0..4095 float4 groups
            int row = idx >> 6;
            int k0  = (idx & 63) * 4;
            int gn  = node0 + row;
            float4 v = make_float4(0.f, 0.f, 0.f, 0.f);
            if (gn < N_NODES) v = *(const float4*)(x + (size_t)gn * D_IN + k0);
            unsigned r0 = (unsigned)f2bf(v.x) | ((unsigned)f2bf(v.y) << 16);
            unsigned r1 = (unsigned)f2bf(v.z) | ((unsigned)f2bf(v.w) << 16);
            int kblk = k0 >> 5, q4 = (k0 & 31) >> 3, rem = k0 & 7;
            int sidx = ((kblk * 4 + (row >> 4)) * 64 + q4 * 16 + (row & 15)) * 8 + rem;
            *(uint2*)&As[sidx] = make_uint2(r0, r1);
        }
        __syncthreads();

        f32x4 acc[4][2];
#pragma unroll
        for (int i = 0; i < 4; ++i)
#pragma unroll
            for (int j = 0; j < 2; ++j) { acc[i][j][0]=0.f; acc[i][j][1]=0.f; acc[i][j][2]=0.f; acc[i][j][3]=0.f; }

#pragma unroll
        for (int kb = 0; kb < 8; ++kb) {             // K = 256
            bf16x8 af[4], bfr[2];
#pragma unroll
            for (int nt = 0; nt < 4; ++nt)
                af[nt] = *(const bf16x8*)&As[(((kb * 4 + nt) * 64) + lane) * 8];
#pragma unroll
            for (int ft = 0; ft < 2; ++ft)
                bfr[ft] = *(const bf16x8*)&wfc[((kb * 8 + wid * 2 + ft) * 64 + lane) * 8];
#pragma unroll
            for (int nt = 0; nt < 4; ++nt)
#pragma unroll
                for (int ft = 0; ft < 2; ++ft)
                    acc[nt][ft] = __builtin_amdgcn_mfma_f32_16x16x32_bf16(af[nt], bfr[ft], acc[nt][ft], 0, 0, 0);
        }
        __syncthreads();                              // As dead; reuse

#pragma unroll
        for (int ft = 0; ft < 2; ++ft) {
            int feat = wid * 32 + ft * 16 + lm;
            float bb = b[feat];
#pragma unroll
            for (int nt = 0; nt < 4; ++nt)
#pragma unroll
                for (int r = 0; r < 4; ++r) {
                    float vv = fmaxf(acc[nt][ft][r] + bb, 0.f);
                    int sidx = ((wid * 4 + nt) * 64 + (ft * 2 + (lm >> 3)) * 16 + quad * 4 + r) * 8 + (lm & 7);
                    As[sidx] = f2bf(vv);
                }
        }
        __syncthreads();
        unsigned short* hdst = hfrag + (size_t)blockIdx.x * 8192;
#pragma unroll
        for (int i = 0; i < 4; ++i) {
            int idx = tid + i * 256;
            *(uint4*)(hdst + idx * 8) = *(const uint4*)&As[idx * 8];
        }
    } else {
        // ---- scan: exclusive prefix of deg -> offs, cursor (1 block) ----
        // LDS-tiled: coalesced global reads, per-chunk work from LDS.
        __shared__ int wsum[4];
        int* tile = (int*)As;                        // 8192 ints per tile
        const int PT = 196;                          // 256*196 = 50176 >= 50000
        int base = tid * PT;
        int cnt = (base < N_NODES) ? min(PT, N_NODES - base) : 0;

        // phase A: per-thread chunk sums
        int s = 0;
        for (int t0 = 0; t0 < N_NODES; t0 += 8192) {
            int n = min(8192, N_NODES - t0);
            for (int i = tid; i < n; i += 256) tile[i] = deg[t0 + i];
            __syncthreads();
            int lo = (base > t0) ? base : t0;
            int hi = min(base + cnt, t0 + n);
            for (int i = lo; i < hi; ++i) s += tile[i - t0];
            __syncthreads();
        }
        // block scan of the 256 sums
        int lane = tid & 63, w = tid >> 6;
        int v = s;
        for (int off = 1; off < 64; off <<= 1) {
            int t = __shfl_up(v, off, 64);
            if (lane >= off) v += t;
        }
        if (lane == 63) wsum[w] = v;
        __syncthreads();
        int woff = 0;
        for (int i = 0; i < w; ++i) woff += wsum[i];
        int run = woff + v - s;                      // exclusive prefix for chunk

        // phase B: write offs/cursor
        for (int t0 = 0; t0 < N_NODES; t0 += 8192) {
            int n = min(8192, N_NODES - t0);
            __syncthreads();
            for (int i = tid; i < n; i += 256) tile[i] = deg[t0 + i];
            __syncthreads();
            int lo = (base > t0) ? base : t0;
            int hi = min(base + cnt, t0 + n);
            for (int i = lo; i < hi; ++i) {
                offs[i] = run;
                cursor[i] = run;
                run += tile[i - t0];
            }
        }
        if (tid == 0) offs[N_NODES] = E_EDGES;
    }
}

// ================= D3: [qkvs | fill] =================
__global__ __launch_bounds__(256) void k_d3(const unsigned short* __restrict__ hfrag,
                                            const unsigned short* __restrict__ wsw,
                                            const float* __restrict__ bq,
                                            const float* __restrict__ bk,
                                            const float* __restrict__ bv,
                                            const float* __restrict__ bs,
                                            unsigned short* __restrict__ qo,
                                            unsigned short* __restrict__ kv,
                                            float* __restrict__ out,
                                            const int* __restrict__ ei,
                                            int* __restrict__ cursor,
                                            int* __restrict__ ssrc) {
    const int tid = threadIdx.x;
    if (blockIdx.x < NBLK * 4) {
        const int tile = blockIdx.x >> 2;
        const int sel  = blockIdx.x & 3;
        const unsigned short* W = wsw + 32768 + sel * 16384;
        const float* b = (sel == 0) ? bq : (sel == 1) ? bk : (sel == 2) ? bv : bs;
        const int lane = tid & 63;
        const int wid  = tid >> 6;
        const int lm   = lane & 15;
        const int quad = lane >> 4;
        const int node0 = tile * MT;
        const unsigned short* hsrc = hfrag + (size_t)tile * 8192;

        f32x4 acc[4][2];
#pragma unroll
        for (int i = 0; i < 4; ++i)
#pragma unroll
            for (int j = 0; j < 2; ++j) { acc[i][j][0]=0.f; acc[i][j][1]=0.f; acc[i][j][2]=0.f; acc[i][j][3]=0.f; }

#pragma unroll
        for (int kb = 0; kb < 4; ++kb) {             // K = 128
            bf16x8 af[4], bfr[2];
#pragma unroll
            for (int nt = 0; nt < 4; ++nt)
                af[nt] = *(const bf16x8*)&hsrc[((kb * 4 + nt) * 64 + lane) * 8];
#pragma unroll
            for (int ft = 0; ft < 2; ++ft)
                bfr[ft] = *(const bf16x8*)&W[((kb * 8 + wid * 2 + ft) * 64 + lane) * 8];
#pragma unroll
            for (int nt = 0; nt < 4; ++nt)
#pragma unroll
                for (int ft = 0; ft < 2; ++ft)
                    acc[nt][ft] = __builtin_amdgcn_mfma_f32_16x16x32_bf16(af[nt], bfr[ft], acc[nt][ft], 0, 0, 0);
        }
#pragma unroll
        for (int ft = 0; ft < 2; ++ft) {
            int feat = wid * 32 + ft * 16 + lm;
            float bb = b[feat];
#pragma unroll
            for (int nt = 0; nt < 4; ++nt)
#pragma unroll
                for (int r = 0; r < 4; ++r) {
                    int gn = node0 + nt * 16 + quad * 4 + r;
                    if (gn < N_NODES) {
                        float vv = acc[nt][ft][r] + bb;
                        if (sel == 0)      qo[(size_t)gn * D_OUT + feat] = f2bf(vv);
                        else if (sel == 1) kv[(size_t)gn * 256 + feat] = f2bf(vv);
                        else if (sel == 2) kv[(size_t)gn * 256 + 128 + feat] = f2bf(vv);
                        else               out[(size_t)gn * D_OUT + feat] = vv;
                    }
                }
        }
    } else {
        int e = (blockIdx.x - NBLK * 4) * 256 + tid;
        if (e < E_EDGES) {
            int d = ei[E_EDGES + e];
            int p = atomicAdd(&cursor[d], 1);
            ssrc[p] = ei[e];
        }
    }
}

// ================= D4: aggregation =================
// one wave/node; 4 independent 16-lane groups, each owning one edge at a time.
// No running max (scores provably tiny for this model), so softmax is a plain
// sum of exp — no serial rescale chain.
__global__ __launch_bounds__(256) void k_agg(const unsigned short* __restrict__ q,
                                             const unsigned short* __restrict__ kv,
                                             const int* __restrict__ offs,
                                             const int* __restrict__ ssrc,
                                             float* __restrict__ out) {
    const int wid  = threadIdx.x >> 6;
    const int lane = threadIdx.x & 63;
    const int node = blockIdx.x * 4 + wid;
    if (node >= N_NODES) return;
    const int beg = offs[node];
    const int end = offs[node + 1];
    if (beg == end) return;                       // out already holds skip

    const int g = lane >> 4;                      // group 0..3 (edge slot)
    const int c = lane & 15;                      // channel chunk (8 ch)

    float qf[8];
    {
        bf16x8 qv = *(const bf16x8*)(q + (size_t)node * D_OUT + c * 8);
#pragma unroll
        for (int i = 0; i < 8; ++i) qf[i] = bf2f((unsigned short)qv[i]);
    }
    const float scale = 0.08838834764831845f;     // 1/sqrt(128)
    float l = 0.f;
    float acc[8];
#pragma unroll
    for (int i = 0; i < 8; ++i) acc[i] = 0.f;

    for (int p = beg; p < end; p += 4) {
        int pg = p + g;
        int j = ssrc[(pg < end) ? pg : (end - 1)];
        bf16x8 kvec = *(const bf16x8*)(kv + (size_t)j * 256 + c * 8);
        bf16x8 vvec = *(const bf16x8*)(kv + (size_t)j * 256 + 128 + c * 8);
        float s = 0.f;
#pragma unroll
        for (int i = 0; i < 8; ++i) s += bf2f((unsigned short)kvec[i]) * qf[i];
#pragma unroll
        for (int off = 1; off < 16; off <<= 1) s += __shfl_xor(s, off, 64);
        float e = (pg < end) ? __expf(s * scale) : 0.f;
        l += e;
#pragma unroll
        for (int i = 0; i < 8; ++i) acc[i] += e * bf2f((unsigned short)vvec[i]);
    }
    // merge the 4 groups (cross-group butterfly; lanes keep same channel c)
#pragma unroll
    for (int off = 16; off < 64; off <<= 1) {
        l += __shfl_xor(l, off, 64);
#pragma unroll
        for (int i = 0; i < 8; ++i) acc[i] += __shfl_xor(acc[i], off, 64);
    }
    if (g == 0) {
        float inv = 1.f / l;
        float* orow = out + (size_t)node * D_OUT + c * 8;
        float4 o0 = *(const float4*)(orow);
        float4 o1 = *(const float4*)(orow + 4);
        o0.x += acc[0] * inv; o0.y += acc[1] * inv; o0.z += acc[2] * inv; o0.w += acc[3] * inv;
        o1.x += acc[4] * inv; o1.y += acc[5] * inv; o1.z += acc[6] * inv; o1.w += acc[7] * inv;
        *(float4*)(orow)     = o0;
        *(float4*)(orow + 4) = o1;
    }
}

// ---------------- host launch ----------------
extern "C" void kernel_launch(void* const* d_in, const int* in_sizes, int n_in,
                              void* d_out, int out_size, void* d_ws, size_t ws_size,
                              hipStream_t stream) {
    const float* x     = (const float*)d_in[0];
    const int*   ei    = (const int*)d_in[1];
    const float* W_fc  = (const float*)d_in[2];
    const float* b_fc  = (const float*)d_in[3];
    const float* W_q   = (const float*)d_in[4];
    const float* b_q   = (const float*)d_in[5];
    const float* W_k   = (const float*)d_in[6];
    const float* b_k   = (const float*)d_in[7];
    const float* W_v   = (const float*)d_in[8];
    const float* b_v   = (const float*)d_in[9];
    const float* W_s   = (const float*)d_in[10];
    const float* b_s   = (const float*)d_in[11];
    float* out = (float*)d_out;

    // ws layout: q bf16 12.8MB | kv bf16 25.6MB | hfrag bf16 12.8MB |
    //            wsw bf16 196KB | CSR ~3.8MB  => ~55 MB total (< ws_size)
    unsigned short* qb    = (unsigned short*)d_ws;
    unsigned short* kvb   = qb + (size_t)N_NODES * D_OUT;
    unsigned short* hfrag = kvb + (size_t)N_NODES * 256;
    unsigned short* wsw   = hfrag + (size_t)NBLK * 8192;
    int* deg    = (int*)(wsw + 98304);
    int* offs   = deg + N_NODES;          // N+1 entries
    int* cursor = offs + (N_NODES + 1);
    int* ssrc   = cursor + N_NODES;       // E entries

    hipMemsetAsync(deg, 0, N_NODES * sizeof(int), stream);

    k_d1<<<96 + NB_DEG, 256, 0, stream>>>(W_fc, W_q, W_k, W_v, W_s, wsw, ei, deg);
    k_d2<<<NBLK + 1, 256, 0, stream>>>(x, wsw, b_fc, hfrag, deg, offs, cursor);
    k_d3<<<NBLK * 4 + NB_DEG, 256, 0, stream>>>(hfrag, wsw, b_q, b_k, b_v, b_s,
                                                qb, kvb, out, ei, cursor, ssrc);
    k_agg<<<(N_NODES + 3) / 4, 256, 0, stream>>>(qb, kvb, offs, ssrc, out);
}

// Round 8
// 322.369 us; speedup vs baseline: 1.2689x; 1.1908x over previous
//
#include <hip/hip_runtime.h>
#include <math.h>

#define N_NODES 50000
#define E_EDGES 800000
#define D_IN    256
#define D_H     128
#define D_OUT   128

#define MT    64                          // nodes per GEMM tile
#define NBLK  ((N_NODES + MT - 1) / MT)   // 782
#define NB_DEG ((E_EDGES + 255) / 256)    // 3125

typedef __attribute__((ext_vector_type(8))) short bf16x8;
typedef __attribute__((ext_vector_type(4))) float f32x4;

__device__ __forceinline__ unsigned short f2bf(float f) {
    unsigned u = __float_as_uint(f);
    return (unsigned short)((u + 0x7FFFu + ((u >> 16) & 1u)) >> 16);
}
__device__ __forceinline__ float bf2f(unsigned short u) {
    return __uint_as_float((unsigned)u << 16);
}

// Fragment layouts (16x16x32 bf16 MFMA), verified R3-R7:
//   A-frag: lane(lm,quad) holds A[m=blk*16+lm][k=kblk*32+quad*8 ..+8]
//   B-frag: lane holds W[n=blk*16+lm][k=...]
//   C/D:    col = lane&15, row = quad*4 + reg
// Packed: chunk c = (kblk*N16 + blk)*64 + lane -> shorts c*8..+8 (lane-linear).
// fc LDS A-tile uses chunk^kblk swizzle (write: spreads banks; read: still
// lane-linear since kblk is wave-uniform per instruction).

// ================= D1: [wconv | deg] =================
__global__ __launch_bounds__(256) void k_d1(const float* __restrict__ Wfc,
                                            const float* __restrict__ Wq,
                                            const float* __restrict__ Wk,
                                            const float* __restrict__ Wv,
                                            const float* __restrict__ Ws,
                                            unsigned short* __restrict__ wsw,
                                            const int* __restrict__ ei,
                                            int* __restrict__ deg) {
    if (blockIdx.x < 96) {
        int g = blockIdx.x * 256 + threadIdx.x;      // 0..24575 float4 groups
        const float* src; unsigned short* dst; int n, k0;
        if (g < 8192) {                               // W_fc: 128 x 256
            src = Wfc; dst = wsw;
            n = g >> 6; k0 = (g & 63) * 4;
        } else {
            int t = (g - 8192) >> 12;                 // 0..3
            int pos = (g - 8192) & 4095;              // 128 x 128
            src = (t == 0) ? Wq : (t == 1) ? Wk : (t == 2) ? Wv : Ws;
            dst = wsw + 32768 + t * 16384;
            n = pos >> 5; k0 = (pos & 31) * 4;
        }
        float4 v = *(const float4*)(src + (size_t)n * ((g < 8192) ? 256 : 128) + k0);
        unsigned r0 = (unsigned)f2bf(v.x) | ((unsigned)f2bf(v.y) << 16);
        unsigned r1 = (unsigned)f2bf(v.z) | ((unsigned)f2bf(v.w) << 16);
        int kblk = k0 >> 5, quad = (k0 & 31) >> 3, rem = k0 & 7;
        int sidx = (((kblk * 8 + (n >> 4)) * 4 + quad) * 16 + (n & 15)) * 8 + rem;
        *(uint2*)&dst[sidx] = make_uint2(r0, r1);
    } else {
        int e = (blockIdx.x - 96) * 256 + threadIdx.x;
        if (e < E_EDGES) atomicAdd(&deg[ei[E_EDGES + e]], 1);
    }
}

// ================= D2: [fc | scan] =================
__global__ __launch_bounds__(256) void k_d2(const float* __restrict__ x,
                                            const unsigned short* __restrict__ wfc,
                                            const float* __restrict__ b,
                                            unsigned short* __restrict__ hfrag,
                                            const int* __restrict__ deg,
                                            int* __restrict__ offs,
                                            int* __restrict__ cursor) {
    const int tid = threadIdx.x;
    if (blockIdx.x < NBLK) {
        // ---- fc: h = relu(x @ W_fc^T + b_fc), frag-packed bf16 out ----
        __shared__ __align__(16) unsigned short As[MT * D_IN];   // 32 KB
        const int lane = tid & 63;
        const int wid  = tid >> 6;
        const int lm   = lane & 15;
        const int quad = lane >> 4;
        const int node0 = blockIdx.x * MT;

#pragma unroll
        for (int i = 0; i < 16; ++i) {
            int idx = tid + i * 256;                 // 0..4095 float4 groups
            int row = idx >> 6;
            int k0  = (idx & 63) * 4;
            int gn  = node0 + row;
            float4 v = make_float4(0.f, 0.f, 0.f, 0.f);
            if (gn < N_NODES) v = *(const float4*)(x + (size_t)gn * D_IN + k0);
            unsigned r0 = (unsigned)f2bf(v.x) | ((unsigned)f2bf(v.y) << 16);
            unsigned r1 = (unsigned)f2bf(v.z) | ((unsigned)f2bf(v.w) << 16);
            int kblk = k0 >> 5, q4 = (k0 & 31) >> 3, rem = k0 & 7;
            int chunk = ((kblk * 4 + (row >> 4)) * 64 + q4 * 16 + (row & 15)) ^ kblk;
            *(uint2*)&As[chunk * 8 + rem] = make_uint2(r0, r1);
        }
        __syncthreads();

        f32x4 acc[4][2];
#pragma unroll
        for (int i = 0; i < 4; ++i)
#pragma unroll
            for (int j = 0; j < 2; ++j) { acc[i][j][0]=0.f; acc[i][j][1]=0.f; acc[i][j][2]=0.f; acc[i][j][3]=0.f; }

#pragma unroll
        for (int kb = 0; kb < 8; ++kb) {             // K = 256
            bf16x8 af[4], bfr[2];
#pragma unroll
            for (int nt = 0; nt < 4; ++nt)
                af[nt] = *(const bf16x8*)&As[((((kb * 4 + nt) * 64) + lane) ^ kb) * 8];
#pragma unroll
            for (int ft = 0; ft < 2; ++ft)
                bfr[ft] = *(const bf16x8*)&wfc[((kb * 8 + wid * 2 + ft) * 64 + lane) * 8];
#pragma unroll
            for (int nt = 0; nt < 4; ++nt)
#pragma unroll
                for (int ft = 0; ft < 2; ++ft)
                    acc[nt][ft] = __builtin_amdgcn_mfma_f32_16x16x32_bf16(af[nt], bfr[ft], acc[nt][ft], 0, 0, 0);
        }
        __syncthreads();                              // As dead; reuse

#pragma unroll
        for (int ft = 0; ft < 2; ++ft) {
            int feat = wid * 32 + ft * 16 + lm;
            float bb = b[feat];
#pragma unroll
            for (int nt = 0; nt < 4; ++nt)
#pragma unroll
                for (int r = 0; r < 4; ++r) {
                    float vv = fmaxf(acc[nt][ft][r] + bb, 0.f);
                    int sidx = ((wid * 4 + nt) * 64 + (ft * 2 + (lm >> 3)) * 16 + quad * 4 + r) * 8 + (lm & 7);
                    As[sidx] = f2bf(vv);
                }
        }
        __syncthreads();
        unsigned short* hdst = hfrag + (size_t)blockIdx.x * 8192;
#pragma unroll
        for (int i = 0; i < 4; ++i) {
            int idx = tid + i * 256;
            *(uint4*)(hdst + idx * 8) = *(const uint4*)&As[idx * 8];
        }
    } else {
        // ---- scan: exclusive prefix of deg -> offs, cursor (1 block) ----
        // Register-tiled: 4x int4 loads per 16 elems (pipelined), VALU sums.
        __shared__ int wsum[4];
        const int PT = 196;                          // 256*196 = 50176 >= 50000
        int base = tid * PT;                         // 784 B/thread, 16B aligned
        int cnt = (base < N_NODES) ? min(PT, N_NODES - base) : 0;

        int s = 0;
        for (int c0 = 0; c0 + 16 <= cnt; c0 += 16) {
            int4 a = *(const int4*)&deg[base + c0];
            int4 b4 = *(const int4*)&deg[base + c0 + 4];
            int4 c4 = *(const int4*)&deg[base + c0 + 8];
            int4 d4 = *(const int4*)&deg[base + c0 + 12];
            s += a.x + a.y + a.z + a.w + b4.x + b4.y + b4.z + b4.w
               + c4.x + c4.y + c4.z + c4.w + d4.x + d4.y + d4.z + d4.w;
        }
        for (int i = cnt & ~15; i < cnt; ++i) s += deg[base + i];

        int lane = tid & 63, w = tid >> 6;
        int v = s;
        for (int off = 1; off < 64; off <<= 1) {
            int t = __shfl_up(v, off, 64);
            if (lane >= off) v += t;
        }
        if (lane == 63) wsum[w] = v;
        __syncthreads();
        int woff = 0;
        for (int i = 0; i < w; ++i) woff += wsum[i];
        int run = woff + v - s;                      // exclusive prefix

        for (int c0 = 0; c0 + 16 <= cnt; c0 += 16) {
            int d16[16];
            *(int4*)&d16[0]  = *(const int4*)&deg[base + c0];
            *(int4*)&d16[4]  = *(const int4*)&deg[base + c0 + 4];
            *(int4*)&d16[8]  = *(const int4*)&deg[base + c0 + 8];
            *(int4*)&d16[12] = *(const int4*)&deg[base + c0 + 12];
            int o16[16];
#pragma unroll
            for (int j = 0; j < 16; ++j) { o16[j] = run; run += d16[j]; }
#pragma unroll
            for (int j = 0; j < 4; ++j) {
                *(int4*)&offs[base + c0 + j * 4]   = *(const int4*)&o16[j * 4];
                *(int4*)&cursor[base + c0 + j * 4] = *(const int4*)&o16[j * 4];
            }
        }
        for (int i = cnt & ~15; i < cnt; ++i) {
            offs[i + base] = run;
            cursor[i + base] = run;
            run += deg[base + i];
        }
        if (tid == 0) offs[N_NODES] = E_EDGES;
    }
}

// ================= D3: [qkvs | fill] =================
__global__ __launch_bounds__(256) void k_d3(const unsigned short* __restrict__ hfrag,
                                            const unsigned short* __restrict__ wsw,
                                            const float* __restrict__ bq,
                                            const float* __restrict__ bk,
                                            const float* __restrict__ bv,
                                            const float* __restrict__ bs,
                                            unsigned short* __restrict__ qo,
                                            unsigned short* __restrict__ kv,
                                            float* __restrict__ out,
                                            const int* __restrict__ ei,
                                            int* __restrict__ cursor,
                                            int* __restrict__ ssrc) {
    const int tid = threadIdx.x;
    if (blockIdx.x < NBLK * 4) {
        const int tile = blockIdx.x >> 2;
        const int sel  = blockIdx.x & 3;
        const unsigned short* W = wsw + 32768 + sel * 16384;
        const float* b = (sel == 0) ? bq : (sel == 1) ? bk : (sel == 2) ? bv : bs;
        const int lane = tid & 63;
        const int wid  = tid >> 6;
        const int lm   = lane & 15;
        const int quad = lane >> 4;
        const int node0 = tile * MT;
        const unsigned short* hsrc = hfrag + (size_t)tile * 8192;

        f32x4 acc[4][2];
#pragma unroll
        for (int i = 0; i < 4; ++i)
#pragma unroll
            for (int j = 0; j < 2; ++j) { acc[i][j][0]=0.f; acc[i][j][1]=0.f; acc[i][j][2]=0.f; acc[i][j][3]=0.f; }

#pragma unroll
        for (int kb = 0; kb < 4; ++kb) {             // K = 128
            bf16x8 af[4], bfr[2];
#pragma unroll
            for (int nt = 0; nt < 4; ++nt)
                af[nt] = *(const bf16x8*)&hsrc[((kb * 4 + nt) * 64 + lane) * 8];
#pragma unroll
            for (int ft = 0; ft < 2; ++ft)
                bfr[ft] = *(const bf16x8*)&W[((kb * 8 + wid * 2 + ft) * 64 + lane) * 8];
#pragma unroll
            for (int nt = 0; nt < 4; ++nt)
#pragma unroll
                for (int ft = 0; ft < 2; ++ft)
                    acc[nt][ft] = __builtin_amdgcn_mfma_f32_16x16x32_bf16(af[nt], bfr[ft], acc[nt][ft], 0, 0, 0);
        }
#pragma unroll
        for (int ft = 0; ft < 2; ++ft) {
            int feat = wid * 32 + ft * 16 + lm;
            float bb = b[feat];
#pragma unroll
            for (int nt = 0; nt < 4; ++nt)
#pragma unroll
                for (int r = 0; r < 4; ++r) {
                    int gn = node0 + nt * 16 + quad * 4 + r;
                    if (gn < N_NODES) {
                        float vv = acc[nt][ft][r] + bb;
                        if (sel == 0)      qo[(size_t)gn * D_OUT + feat] = f2bf(vv);
                        else if (sel == 1) kv[(size_t)gn * 256 + feat] = f2bf(vv);
                        else if (sel == 2) kv[(size_t)gn * 256 + 128 + feat] = f2bf(vv);
                        else               out[(size_t)gn * D_OUT + feat] = vv;
                    }
                }
        }
    } else {
        int e = (blockIdx.x - NBLK * 4) * 256 + tid;
        if (e < E_EDGES) {
            int d = ei[E_EDGES + e];
            int p = atomicAdd(&cursor[d], 1);
            ssrc[p] = ei[e];
        }
    }
}

// ================= D4: aggregation =================
// one wave/node; 4 independent 16-lane groups, each owning one edge at a time.
// No running max (scores provably tiny for this model), softmax = plain exp-sum.
__global__ __launch_bounds__(256) void k_agg(const unsigned short* __restrict__ q,
                                             const unsigned short* __restrict__ kv,
                                             const int* __restrict__ offs,
                                             const int* __restrict__ ssrc,
                                             float* __restrict__ out) {
    const int wid  = threadIdx.x >> 6;
    const int lane = threadIdx.x & 63;
    const int node = blockIdx.x * 4 + wid;
    if (node >= N_NODES) return;
    const int beg = offs[node];
    const int end = offs[node + 1];
    if (beg == end) return;                       // out already holds skip

    const int g = lane >> 4;                      // group 0..3 (edge slot)
    const int c = lane & 15;                      // channel chunk (8 ch)

    float qf[8];
    {
        bf16x8 qv = *(const bf16x8*)(q + (size_t)node * D_OUT + c * 8);
#pragma unroll
        for (int i = 0; i < 8; ++i) qf[i] = bf2f((unsigned short)qv[i]);
    }
    const float scale = 0.08838834764831845f;     // 1/sqrt(128)
    float l = 0.f;
    float acc[8];
#pragma unroll
    for (int i = 0; i < 8; ++i) acc[i] = 0.f;

    for (int p = beg; p < end; p += 4) {
        int pg = p + g;
        int j = ssrc[(pg < end) ? pg : (end - 1)];
        bf16x8 kvec = *(const bf16x8*)(kv + (size_t)j * 256 + c * 8);
        bf16x8 vvec = *(const bf16x8*)(kv + (size_t)j * 256 + 128 + c * 8);
        float s = 0.f;
#pragma unroll
        for (int i = 0; i < 8; ++i) s += bf2f((unsigned short)kvec[i]) * qf[i];
#pragma unroll
        for (int off = 1; off < 16; off <<= 1) s += __shfl_xor(s, off, 64);
        float e = (pg < end) ? __expf(s * scale) : 0.f;
        l += e;
#pragma unroll
        for (int i = 0; i < 8; ++i) acc[i] += e * bf2f((unsigned short)vvec[i]);
    }
    // merge the 4 groups (cross-group butterfly; lanes keep same channel c)
#pragma unroll
    for (int off = 16; off < 64; off <<= 1) {
        l += __shfl_xor(l, off, 64);
#pragma unroll
        for (int i = 0; i < 8; ++i) acc[i] += __shfl_xor(acc[i], off, 64);
    }
    if (g == 0) {
        float inv = 1.f / l;
        float* orow = out + (size_t)node * D_OUT + c * 8;
        float4 o0 = *(const float4*)(orow);
        float4 o1 = *(const float4*)(orow + 4);
        o0.x += acc[0] * inv; o0.y += acc[1] * inv; o0.z += acc[2] * inv; o0.w += acc[3] * inv;
        o1.x += acc[4] * inv; o1.y += acc[5] * inv; o1.z += acc[6] * inv; o1.w += acc[7] * inv;
        *(float4*)(orow)     = o0;
        *(float4*)(orow + 4) = o1;
    }
}

// ---------------- host launch ----------------
extern "C" void kernel_launch(void* const* d_in, const int* in_sizes, int n_in,
                              void* d_out, int out_size, void* d_ws, size_t ws_size,
                              hipStream_t stream) {
    const float* x     = (const float*)d_in[0];
    const int*   ei    = (const int*)d_in[1];
    const float* W_fc  = (const float*)d_in[2];
    const float* b_fc  = (const float*)d_in[3];
    const float* W_q   = (const float*)d_in[4];
    const float* b_q   = (const float*)d_in[5];
    const float* W_k   = (const float*)d_in[6];
    const float* b_k   = (const float*)d_in[7];
    const float* W_v   = (const float*)d_in[8];
    const float* b_v   = (const float*)d_in[9];
    const float* W_s   = (const float*)d_in[10];
    const float* b_s   = (const float*)d_in[11];
    float* out = (float*)d_out;

    // ws layout: q bf16 12.8MB | kv bf16 25.6MB | hfrag bf16 12.8MB |
    //            wsw bf16 196KB | CSR ~3.8MB  => ~55 MB total (< ws_size)
    unsigned short* qb    = (unsigned short*)d_ws;
    unsigned short* kvb   = qb + (size_t)N_NODES * D_OUT;
    unsigned short* hfrag = kvb + (size_t)N_NODES * 256;
    unsigned short* wsw   = hfrag + (size_t)NBLK * 8192;
    int* deg    = (int*)(wsw + 98304);    // 16B-aligned
    int* offs   = deg + N_NODES;          // N+1 used, padded to N+4
    int* cursor = offs + (N_NODES + 4);   // 16B-aligned for int4 stores
    int* ssrc   = cursor + N_NODES;       // E entries

    hipMemsetAsync(deg, 0, N_NODES * sizeof(int), stream);

    k_d1<<<96 + NB_DEG, 256, 0, stream>>>(W_fc, W_q, W_k, W_v, W_s, wsw, ei, deg);
    k_d2<<<NBLK + 1, 256, 0, stream>>>(x, wsw, b_fc, hfrag, deg, offs, cursor);
    k_d3<<<NBLK * 4 + NB_DEG, 256, 0, stream>>>(hfrag, wsw, b_q, b_k, b_v, b_s,
                                                qb, kvb, out, ei, cursor, ssrc);
    k_agg<<<(N_NODES + 3) / 4, 256, 0, stream>>>(qb, kvb, offs, ssrc, out);
}